// Round 6
// baseline (623.391 us; speedup 1.0000x reference)
//
#include <hip/hip_runtime.h>
#include <cstdint>
#include <cstddef>

typedef unsigned short u16;
typedef __attribute__((ext_vector_type(8))) __bf16 bf16x8;
typedef __attribute__((ext_vector_type(4))) float f32x4;

#define DD 1024            // D
#define MM 16384           // B*T rows
#define NCH 64             // scan chunks
#define CLEN 64            // chunk length (NCH*CLEN = T = 4096)
#define EPAD 136           // epilogue LDS row stride (128-col bf16 tiles), u16
#define EPAD2 264          // epilogue LDS row stride (256-col bf16 tiles), u16
#define EPADF 260          // epilogue LDS row stride (256-col f32 tiles), f32

__device__ __forceinline__ u16 f2b(float f) {
    uint32_t u = __float_as_uint(f);
    u += 0x7fffu + ((u >> 16) & 1u);       // round-to-nearest-even
    return (u16)(u >> 16);
}
__device__ __forceinline__ float b2f(u16 v) {
    return __uint_as_float(((uint32_t)v) << 16);
}
__device__ __forceinline__ float sigmoid_f(float v) { return 1.f / (1.f + __expf(-v)); }
__device__ __forceinline__ float gelu_f(float v) {
    return 0.5f * v * (1.f + erff(v * 0.70710678118654752f));
}

__device__ __forceinline__ void glds16(const u16* g, u16* l) {
    __builtin_amdgcn_global_load_lds(
        (const __attribute__((address_space(1))) void*)g,
        (__attribute__((address_space(3))) void*)l, 16, 0, 0);
}

// Round-0 swizzle (1024-block grids): groups of 64 = 8 m x 8 n, XCD = l&7.
__device__ __forceinline__ void swiz(int l, int& mt, int& nt) {
    const int g = l >> 6, r = l & 63;
    mt = g * 8 + (r & 7);
    nt = r >> 3;
}
// Round-4 swizzle (512-block grids): XCD x owns m-tiles [8x,8x+8).
__device__ __forceinline__ void swiz8(int l, int& mt, int& nt) {
    mt = (l & 7) * 8 + ((l >> 3) & 7);
    nt = l >> 6;
}

// ---------------------------------------------------------------------------
// ROUND-0-PROVEN narrow GEMM (verbatim except __launch_bounds__ 2nd arg):
// out[m,n] = sum_k A[m,k]*W[n,k] + bias[n]. 128x128 tile, BK=32, 256 threads
// (4 waves 2x2 of 64x64), double-buffered LDS (32KB), counted vmcnt(4).
// __launch_bounds__(256,3): register diet to the 12-waves/CU bucket
// (64 acc AGPR + <=106 VGPR ~ 170 total). Occupancy lever: all 8-wave/CU
// configs measured 24-29% MfmaUtil; m97-class 12-wave measured 37%.
// MODE 0: bf16 out via LDS-staged coalesced write
// MODE 2: f32 out = v + bias + auxf[idx]
// ---------------------------------------------------------------------------
template <int MODE>
__global__ __launch_bounds__(256, 3)
void gemm_bt(const u16* __restrict__ A, const u16* __restrict__ Bw,
             const float* __restrict__ bias, const float* __restrict__ auxf,
             u16* __restrict__ outb, float* __restrict__ outf)
{
    const int K = DD, N = DD;
    __shared__ __align__(16) u16 smem[16384];   // As0 Bs0 As1 Bs1 (4096 u16 each)
    u16* const As0 = smem;
    u16* const Bs0 = smem + 4096;
    u16* const As1 = smem + 8192;
    u16* const Bs1 = smem + 12288;

    int mt, nt; swiz(blockIdx.x, mt, nt);
    const int m0 = mt * 128, n0 = nt * 128;
    const int tid = threadIdx.x;
    const int wave = tid >> 6, lane = tid & 63;
    const int wm = (wave >> 1) * 64, wn = (wave & 1) * 64;
    const int lr = lane & 15, lq = lane >> 4;

    // staging: thread stages LDS slot (trow, tcol); global kb = tcol ^ ((trow>>1)&3)
    const int trow = tid >> 2, tcol = tid & 3;
    const int kswz = (tcol ^ ((trow >> 1) & 3)) * 8;
    const u16* Ag = A + (size_t)(m0 + trow) * K + kswz;
    const u16* Bg = Bw + (size_t)(n0 + trow) * K + kswz;
    const int st = tid * 8;
    const int cs = (lq ^ ((lr >> 1) & 3)) * 8;

    f32x4 acc[4][4] = {};

    // prologue: tile 0 -> buf0
    glds16(Ag, As0 + st);
    glds16(Ag + (size_t)64 * K, As0 + st + 2048);
    glds16(Bg, Bs0 + st);
    glds16(Bg + (size_t)64 * K, Bs0 + st + 2048);

#pragma unroll 2
    for (int k0 = 0; k0 < K; k0 += 32) {
        u16* const Ac = ((k0 >> 5) & 1) ? As1 : As0;
        u16* const Bc = ((k0 >> 5) & 1) ? Bs1 : Bs0;
        if (k0 + 32 < K) {
            u16* const An = ((k0 >> 5) & 1) ? As0 : As1;
            u16* const Bn = ((k0 >> 5) & 1) ? Bs0 : Bs1;
            const int kn = k0 + 32;
            glds16(Ag + kn, An + st);
            glds16(Ag + (size_t)64 * K + kn, An + st + 2048);
            glds16(Bg + kn, Bn + st);
            glds16(Bg + (size_t)64 * K + kn, Bn + st + 2048);
            asm volatile("s_waitcnt vmcnt(4)\ns_barrier" ::: "memory");
        } else {
            asm volatile("s_waitcnt vmcnt(0)\ns_barrier" ::: "memory");
        }

        bf16x8 av[4], bv[4];
#pragma unroll
        for (int i = 0; i < 4; i++)
            av[i] = *(const bf16x8*)&Ac[(wm + i * 16 + lr) * 32 + cs];
#pragma unroll
        for (int j = 0; j < 4; j++)
            bv[j] = *(const bf16x8*)&Bc[(wn + j * 16 + lr) * 32 + cs];
#pragma unroll
        for (int i = 0; i < 4; i++)
#pragma unroll
            for (int j = 0; j < 4; j++)
                acc[i][j] = __builtin_amdgcn_mfma_f32_16x16x32_bf16(
                    av[i], bv[j], acc[i][j], 0, 0, 0);
        asm volatile("s_barrier" ::: "memory");   // protect buffer from overwrite
    }

    // epilogue: C/D layout col=lane&15, row=(lane>>4)*4+reg
    if constexpr (MODE == 0) {
        for (int half = 0; half < 2; half++) {
            __syncthreads();
            if (wm == half * 64) {
#pragma unroll
                for (int i = 0; i < 4; i++)
#pragma unroll
                    for (int j = 0; j < 4; j++) {
                        const int col = wn + j * 16 + lr;
                        const float bz = bias[n0 + col];
#pragma unroll
                        for (int p = 0; p < 4; p++)
                            smem[(i * 16 + lq * 4 + p) * EPAD + col] =
                                f2b(acc[i][j][p] + bz);
                    }
            }
            __syncthreads();
#pragma unroll
            for (int t = 0; t < 4; t++) {
                const int f = t * 256 + tid;
                const int row = f >> 4, c8 = (f & 15) * 8;
                *(uint4*)&outb[(size_t)(m0 + half * 64 + row) * N + n0 + c8] =
                    *(const uint4*)&smem[row * EPAD + c8];
            }
        }
    } else {
#pragma unroll
        for (int i = 0; i < 4; i++) {
            const int mrow = m0 + wm + i * 16 + lq * 4;
#pragma unroll
            for (int j = 0; j < 4; j++) {
                const int ncol = n0 + wn + j * 16 + lr;
                const float bz = bias[ncol];
#pragma unroll
                for (int p = 0; p < 4; p++) {
                    const size_t idx = (size_t)(mrow + p) * N + ncol;
                    outf[idx] = acc[i][j][p] + bz + auxf[idx];
                }
            }
        }
    }
}

// ---------------------------------------------------------------------------
// ROUND-4-PROVEN wide GEMM (verbatim): 2-phase-per-K-tile, BM=256, BN=256,
// BK=32, 512 threads (8 waves 2x4, per-wave 128x64), 4-deep ring (128KB),
// prefetch distance 3, counted vmcnt(8). Occupancy-frozen at 8 waves/CU
// (128 acc AGPR + ~116 VGPR ~ 244 regs) — used only for the N=2048 ops.
// MODE 1: bf16 out (N=2048), sigmoid, interleaved bias
// MODE 3: interleaved pair -> out[j] = gelu(sigmoid(v[2j]+b1[j]))*(v[2j+1]+b2[j])
// ---------------------------------------------------------------------------
#define ACC(i, j) ((i) < 4 ? accL[(i) & 3][(j)] : accH[(i) & 3][(j)])

template <int MODE>
__global__ __launch_bounds__(512, 2)
void gemm256(const u16* __restrict__ A, const u16* __restrict__ Bw,
             const float* __restrict__ bias, const float* __restrict__ biasB,
             u16* __restrict__ outb)
{
    __shared__ __align__(16) u16 smem[65536];   // ring: 4 x (A 8192 + B 8192) u16

    int mt, nt; swiz8(blockIdx.x, mt, nt);
    const int m0 = mt * 256, n0 = nt * 256;
    const int tid = threadIdx.x;
    const int wave = tid >> 6, lane = tid & 63;
    const int wm = (wave >> 2) * 128, wn = (wave & 3) * 64;
    const int lr = lane & 15, lq = lane >> 4;

    const int trow = tid >> 2, tcol = tid & 3;
    const int kswz = (tcol ^ ((trow >> 1) & 3)) * 8;
    const u16* Ag = A + (size_t)(m0 + trow) * DD + kswz;
    const u16* Bg = Bw + (size_t)(n0 + trow) * DD + kswz;
    const int st = tid * 8;
    const int cs = (lq ^ ((lr >> 1) & 3)) * 8;

    f32x4 accL[4][4] = {}, accH[4][4] = {};
    bf16x8 av[4], bv[4];

    auto SA = [&](int kt) {
        u16* Ls = smem + (kt & 3) * 16384;
        const u16* a = Ag + (size_t)kt * 32;
        glds16(a, Ls + st);
        glds16(a + (size_t)128 * DD, Ls + 4096 + st);
    };
    auto SB = [&](int kt) {
        u16* Ls = smem + (kt & 3) * 16384 + 8192;
        const u16* b = Bg + (size_t)kt * 32;
        glds16(b, Ls + st);
        glds16(b + (size_t)128 * DD, Ls + 4096 + st);
    };
    auto RDA = [&](int kt, int rb) {
        const u16* Ls = smem + (kt & 3) * 16384;
#pragma unroll
        for (int i = 0; i < 4; i++)
            av[i] = *(const bf16x8*)&Ls[(rb + i * 16 + lr) * 32 + cs];
    };
    auto RDB = [&](int kt) {
        const u16* Ls = smem + (kt & 3) * 16384 + 8192;
#pragma unroll
        for (int j = 0; j < 4; j++)
            bv[j] = *(const bf16x8*)&Ls[(wn + j * 16 + lr) * 32 + cs];
    };
    auto MM16 = [&](f32x4 (&ac)[4][4]) {
        __builtin_amdgcn_s_setprio(1);
#pragma unroll
        for (int i = 0; i < 4; i++)
#pragma unroll
            for (int j = 0; j < 4; j++)
                ac[i][j] = __builtin_amdgcn_mfma_f32_16x16x32_bf16(
                    av[i], bv[j], ac[i][j], 0, 0, 0);
        __builtin_amdgcn_s_setprio(0);
    };

    // prologue: 3 K-tiles in flight; drain to 8 => tile 0 landed
    SA(0); SB(0); SA(1); SB(1); SA(2); SB(2);
    asm volatile("s_waitcnt vmcnt(8)\ns_barrier" ::: "memory");

#pragma unroll 4
    for (int kt = 0; kt < 29; ++kt) {
        RDA(kt, wm); RDB(kt);
        SA(kt + 3);
        asm volatile("s_barrier" ::: "memory");
        MM16(accL);
        asm volatile("s_barrier" ::: "memory");
        RDA(kt, wm + 64);
        SB(kt + 3);
        asm volatile("s_waitcnt vmcnt(8)\ns_barrier" ::: "memory");  // kt+1 landed
        MM16(accH);
        asm volatile("s_barrier" ::: "memory");
    }
    RDA(29, wm); RDB(29);
    asm volatile("s_barrier" ::: "memory");
    MM16(accL);
    asm volatile("s_barrier" ::: "memory");
    RDA(29, wm + 64);
    asm volatile("s_waitcnt vmcnt(4)\ns_barrier" ::: "memory");      // tile 30 landed
    MM16(accH);
    asm volatile("s_barrier" ::: "memory");
    RDA(30, wm); RDB(30);
    asm volatile("s_barrier" ::: "memory");
    MM16(accL);
    asm volatile("s_barrier" ::: "memory");
    RDA(30, wm + 64);
    asm volatile("s_waitcnt vmcnt(0)\ns_barrier" ::: "memory");      // tile 31 landed
    MM16(accH);
    asm volatile("s_barrier" ::: "memory");
    RDA(31, wm); RDB(31);
    MM16(accL);
    RDA(31, wm + 64);
    MM16(accH);

    // epilogues (C/D layout: col=lane&15, row=(lane>>4)*4+reg)
    if constexpr (MODE == 1) {
        u16* ep = smem;
#pragma unroll                               // h compile-time: ACC index (rule #20)
        for (int h = 0; h < 4; ++h) {
            __syncthreads();
            if (wm == (h >> 1) * 128) {
                const int i0 = (h & 1) * 4;
#pragma unroll
                for (int ii = 0; ii < 4; ++ii) {
#pragma unroll
                    for (int j = 0; j < 4; ++j) {
                        const int col = wn + j * 16 + lr;
                        const int gc = n0 + col;
                        const float bz = (gc & 1) ? biasB[gc >> 1] : bias[gc >> 1];
#pragma unroll
                        for (int p = 0; p < 4; ++p)
                            ep[(ii * 16 + lq * 4 + p) * EPAD2 + col] =
                                f2b(sigmoid_f(ACC(i0 + ii, j)[p] + bz));
                    }
                }
            }
            __syncthreads();
#pragma unroll
            for (int t = 0; t < 4; ++t) {
                const int f = t * 512 + tid;
                const int row = f >> 5, c8 = (f & 31) * 8;
                *(uint4*)&outb[(size_t)(m0 + h * 64 + row) * 2048 + n0 + c8] =
                    *(const uint4*)&ep[row * EPAD2 + c8];
            }
        }
    } else {   // MODE 3: interleaved MLP combine, f32 LDS stage
        float* epf = (float*)smem;               // [64][EPADF]
#pragma unroll                               // h compile-time: ACC index (rule #20)
        for (int h = 0; h < 4; ++h) {
            __syncthreads();
            if (wm == (h >> 1) * 128) {
                const int i0 = (h & 1) * 4;
#pragma unroll
                for (int ii = 0; ii < 4; ++ii) {
#pragma unroll
                    for (int j = 0; j < 4; ++j) {
                        const int col = wn + j * 16 + lr;
                        const int gc = n0 + col;
                        const float bz = (gc & 1) ? biasB[gc >> 1] : bias[gc >> 1];
#pragma unroll
                        for (int p = 0; p < 4; ++p)
                            epf[(ii * 16 + lq * 4 + p) * EPADF + col] =
                                ACC(i0 + ii, j)[p] + bz;
                    }
                }
            }
            __syncthreads();
#pragma unroll
            for (int t = 0; t < 4; ++t) {
                const int f = t * 512 + tid;
                const int row = f >> 5, cg = (f & 31) * 4;   // 4 output cols
                const float4 v0 = *(const float4*)&epf[row * EPADF + cg * 2];
                const float4 v1 = *(const float4*)&epf[row * EPADF + cg * 2 + 4];
                ushort4 o4;
                o4.x = f2b(gelu_f(sigmoid_f(v0.x)) * v0.y);
                o4.y = f2b(gelu_f(sigmoid_f(v0.z)) * v0.w);
                o4.z = f2b(gelu_f(sigmoid_f(v1.x)) * v1.y);
                o4.w = f2b(gelu_f(sigmoid_f(v1.z)) * v1.w);
                *(ushort4*)&outb[(size_t)(m0 + h * 64 + row) * DD + (n0 >> 1) + cg] = o4;
            }
        }
    }
}

// ---------------------------------------------------------------------------
// RMSNorm: one block per row; out bf16 = x/max(||x||,1e-12)*sqrt(D)*g
// ---------------------------------------------------------------------------
__global__ __launch_bounds__(256)
void rmsnorm_k(const float* __restrict__ x, const float* __restrict__ g,
               u16* __restrict__ out)
{
    const int row = blockIdx.x;
    const int t = threadIdx.x;
    const float4 v = ((const float4*)(x + (size_t)row * DD))[t];
    float ss = v.x * v.x + v.y * v.y + v.z * v.z + v.w * v.w;
#pragma unroll
    for (int o = 32; o > 0; o >>= 1) ss += __shfl_down(ss, o, 64);
    __shared__ float wsum[4];
    if ((t & 63) == 0) wsum[t >> 6] = ss;
    __syncthreads();
    const float tot = wsum[0] + wsum[1] + wsum[2] + wsum[3];
    const float sc = 32.0f * rsqrtf(fmaxf(tot, 1e-24f));
    const float4 gv = ((const float4*)g)[t];
    ushort4 o4;
    o4.x = f2b(v.x * sc * gv.x);
    o4.y = f2b(v.y * sc * gv.y);
    o4.z = f2b(v.z * sc * gv.z);
    o4.w = f2b(v.w * sc * gv.w);
    ((ushort4*)(out + (size_t)row * DD))[t] = o4;
}

// ---------------------------------------------------------------------------
// fp32 -> bf16 weight conversion.
// conv_plain: 4 plain matrices. conv_inter: 2 row-interleaved pairs
// (dst row 2j = srcA row j, dst row 2j+1 = srcB row j).
// ---------------------------------------------------------------------------
struct WP { const float* s[4]; unsigned off[4]; };
__global__ __launch_bounds__(256)
void conv_plain(WP w, u16* __restrict__ out)
{
    const float* in = w.s[blockIdx.y];
    u16* o = out + (size_t)w.off[blockIdx.y];
    const int i = (blockIdx.x * 256 + threadIdx.x) * 4;
    const float4 v = *(const float4*)(in + i);
    ushort4 r;
    r.x = f2b(v.x); r.y = f2b(v.y); r.z = f2b(v.z); r.w = f2b(v.w);
    *(ushort4*)(o + i) = r;
}
struct WI { const float* a[2]; const float* b[2]; unsigned off[2]; };
__global__ __launch_bounds__(256)
void conv_inter(WI w, u16* __restrict__ out)
{
    u16* o = out + (size_t)w.off[blockIdx.y];
    const int e = (blockIdx.x * 256 + threadIdx.x) * 4;   // < 2M
    const int row = e >> 10, col = e & 1023;
    const float* src = (row & 1) ? w.b[blockIdx.y] : w.a[blockIdx.y];
    const float4 v = *(const float4*)(src + ((size_t)(row >> 1) << 10) + col);
    ushort4 r;
    r.x = f2b(v.x); r.y = f2b(v.y); r.z = f2b(v.z); r.w = f2b(v.w);
    *(ushort4*)(o + e) = r;
}

// ---------------------------------------------------------------------------
// RG-LRU chunked scan, interleaved rt/it input (col 2d = rt, 2d+1 = it).
// h[t] = a[t]*h[t-1] + g[t]; a = exp(log_a * rt / 8); g = sqrt(1-a^2)*it*x
// ---------------------------------------------------------------------------
__global__ __launch_bounds__(256)
void scan_chunks(const u16* __restrict__ rtit, const u16* __restrict__ rg,
                 const float* __restrict__ Lam,
                 float* __restrict__ P, float* __restrict__ Hl)
{
    const int d = blockIdx.x * 256 + threadIdx.x;
    const int c = blockIdx.y, b = blockIdx.z;
    const float k = -log1pf(__expf(-Lam[d])) * 0.125f;
    const size_t base1 = (((size_t)b * 4096) + (size_t)c * CLEN) * DD + d;
    const size_t base2 = (((size_t)b * 4096) + (size_t)c * CLEN) * 2048 + 2 * d;
    float p = 1.f, h = 0.f;
#pragma unroll 4
    for (int t = 0; t < CLEN; t++) {
        const uint32_t w = *(const uint32_t*)&rtit[base2 + (size_t)t * 2048];
        const float r = b2f((u16)(w & 0xffffu));
        const float i = b2f((u16)(w >> 16));
        const float xv = b2f(rg[base1 + (size_t)t * DD]);
        const float a = __expf(k * r);
        const float g = sqrtf(fmaxf(1.f - a * a, 0.f)) * (i * xv);
        p *= a;
        h = fmaf(a, h, g);
    }
    const int o = (b * NCH + c) * DD + d;
    P[o] = p;
    Hl[o] = h;
}

__global__ __launch_bounds__(256)
void scan_carry(const float* __restrict__ P, const float* __restrict__ Hl,
                float* __restrict__ Cin)
{
    const int idx = blockIdx.x * 256 + threadIdx.x;  // B*D = 4096
    const int b = idx >> 10, d = idx & 1023;
    float h = 0.f;
    for (int c = 0; c < NCH; c++) {
        const int o = (b * NCH + c) * DD + d;
        Cin[o] = h;
        h = fmaf(P[o], h, Hl[o]);
    }
}

__global__ __launch_bounds__(256)
void scan_apply(const u16* __restrict__ rtit, const u16* __restrict__ rg,
                const u16* __restrict__ lin, const float* __restrict__ Lam,
                const float* __restrict__ Cin, u16* __restrict__ yin)
{
    const int d = blockIdx.x * 256 + threadIdx.x;
    const int c = blockIdx.y, b = blockIdx.z;
    const float k = -log1pf(__expf(-Lam[d])) * 0.125f;
    const size_t base1 = (((size_t)b * 4096) + (size_t)c * CLEN) * DD + d;
    const size_t base2 = (((size_t)b * 4096) + (size_t)c * CLEN) * 2048 + 2 * d;
    float h = Cin[(b * NCH + c) * DD + d];
#pragma unroll 4
    for (int t = 0; t < CLEN; t++) {
        const uint32_t w = *(const uint32_t*)&rtit[base2 + (size_t)t * 2048];
        const float r = b2f((u16)(w & 0xffffu));
        const float i = b2f((u16)(w >> 16));
        const size_t ix = base1 + (size_t)t * DD;
        const float xv = b2f(rg[ix]);
        const float a = __expf(k * r);
        const float g = sqrtf(fmaxf(1.f - a * a, 0.f)) * (i * xv);
        h = fmaf(a, h, g);
        const float l = b2f(lin[ix]);
        yin[ix] = f2b(gelu_f(l) * h);
    }
}

// ---------------------------------------------------------------------------
extern "C" void kernel_launch(void* const* d_in, const int* in_sizes, int n_in,
                              void* d_out, int out_size, void* d_ws, size_t ws_size,
                              hipStream_t stream)
{
    const float* x      = (const float*)d_in[0];
    const float* g1     = (const float*)d_in[1];
    const float* g2     = (const float*)d_in[2];
    const float* W_lin  = (const float*)d_in[3];
    const float* b_lin  = (const float*)d_in[4];
    const float* W_conv = (const float*)d_in[5];
    const float* b_conv = (const float*)d_in[6];
    const float* W_lin2 = (const float*)d_in[7];
    const float* b_lin2 = (const float*)d_in[8];
    const float* Wa     = (const float*)d_in[9];
    const float* ba     = (const float*)d_in[10];
    const float* Wx     = (const float*)d_in[11];
    const float* bx     = (const float*)d_in[12];
    const float* Lam    = (const float*)d_in[13];
    const float* W1     = (const float*)d_in[14];
    const float* b1     = (const float*)d_in[15];
    const float* W2     = (const float*)d_in[16];
    const float* b2     = (const float*)d_in[17];
    const float* W3     = (const float*)d_in[18];
    const float* b3     = (const float*)d_in[19];
    float* out = (float*)d_out;

    char* p = (char*)d_ws;
    auto alloc = [&](size_t bytes) -> char* {
        char* q = p;
        p += (bytes + 255) & ~(size_t)255;
        return q;
    };
    const size_t MD = (size_t)MM * DD;
    const size_t M1 = (size_t)DD * DD;        // 1M elements
    u16* wball = (u16*)alloc((size_t)8 * M1 * 2);   // 16MB
    u16* t1   = (u16*)alloc(MD * 2);                // lin
    u16* t2   = (u16*)alloc(MD * 2);                // rg, later combined
    u16* t4   = (u16*)alloc(MD * 2);                // xn -> yin -> xm
    u16* rtit = (u16*)alloc(MD * 4);                // interleaved rt/it (16384x2048)
    float* res2 = (float*)alloc(MD * 4);
    float* P   = (float*)alloc((size_t)4 * NCH * DD * 4);
    float* Hl  = (float*)alloc((size_t)4 * NCH * DD * 4);
    float* Cin = (float*)alloc((size_t)4 * NCH * DD * 4);

    // wball layout (u16 elem offsets):
    //  [0]   W_lin   [1M] W_conv   [2M] WaWx(2M, interleaved)
    //  [4M]  W_lin2  [5M] W1W2(2M, interleaved)  [7M] W3
    WP wp;
    wp.s[0] = W_lin;  wp.off[0] = 0;
    wp.s[1] = W_conv; wp.off[1] = 1u << 20;
    wp.s[2] = W_lin2; wp.off[2] = 4u << 20;
    wp.s[3] = W3;     wp.off[3] = 7u << 20;
    conv_plain<<<dim3(M1 / 1024, 4), 256, 0, stream>>>(wp, wball);
    WI wi;
    wi.a[0] = Wa; wi.b[0] = Wx; wi.off[0] = 2u << 20;
    wi.a[1] = W1; wi.b[1] = W2; wi.off[1] = 5u << 20;
    conv_inter<<<dim3(2 * M1 / 1024, 2), 256, 0, stream>>>(wi, wball);

    const u16* wLin  = wball;
    const u16* wConv = wball + (1u << 20);
    const u16* wAX   = wball + (2u << 20);
    const u16* wLin2 = wball + (4u << 20);
    const u16* w12   = wball + (5u << 20);
    const u16* w3    = wball + (7u << 20);

    const int gg = (MM / 128) * (DD / 128);        // 1024 blocks (128x128 tiles)
    const int gw = (MM / 256) * (2 * DD / 256);    // 512 blocks (256x256, N=2048)
    const dim3 sg(DD / 256, NCH, 4);

    // xn = rmsnorm(x)*g1
    rmsnorm_k<<<MM, 256, 0, stream>>>(x, g1, t4);
    // lin = xn@W_lin.T + b_lin
    gemm_bt<0><<<gg, 256, 0, stream>>>(t4, wLin, b_lin, nullptr, t1, nullptr);
    // rg = lin@W_conv.T + b_conv
    gemm_bt<0><<<gg, 256, 0, stream>>>(t1, wConv, b_conv, nullptr, t2, nullptr);
    // rtit = sigmoid(rg@[Wa||Wx interleaved].T + [ba||bx])
    gemm256<1><<<gw, 512, 0, stream>>>(t2, wAX, ba, bx, rtit);
    // RG-LRU scan + yin = gelu(lin)*h
    scan_chunks<<<sg, 256, 0, stream>>>(rtit, t2, Lam, P, Hl);
    scan_carry<<<4096 / 256, 256, 0, stream>>>(P, Hl, Cin);
    scan_apply<<<sg, 256, 0, stream>>>(rtit, t2, t1, Lam, Cin, t4);
    // res2 = yin@W_lin2.T + b_lin2 + x
    gemm_bt<2><<<gg, 256, 0, stream>>>(t4, wLin2, b_lin2, x, nullptr, res2);
    // xm = rmsnorm(res2)*g2
    rmsnorm_k<<<MM, 256, 0, stream>>>(res2, g2, t4);
    // combined = gelu(sigmoid(xm@W1.T+b1)) * (xm@W2.T+b2)   (interleaved pair GEMM)
    gemm256<3><<<gw, 512, 0, stream>>>(t4, w12, b1, b2, t2);
    // y = combined@W3.T + b3 + res2
    gemm_bt<2><<<gg, 256, 0, stream>>>(t2, w3, b3, res2, nullptr, out);
}

// Round 7
// 604.948 us; speedup vs baseline: 1.0305x; 1.0305x over previous
//
#include <hip/hip_runtime.h>
#include <cstdint>
#include <cstddef>

typedef unsigned short u16;
typedef __attribute__((ext_vector_type(8))) __bf16 bf16x8;
typedef __attribute__((ext_vector_type(4))) float f32x4;

#define DD 1024            // D
#define MM 16384           // B*T rows
#define NCH 64             // scan chunks
#define CLEN 64            // chunk length (NCH*CLEN = T = 4096)
#define EPAD2 264          // epilogue LDS row stride (256-col bf16 tiles), u16
#define EPADF 260          // epilogue LDS row stride (256-col f32 tiles), f32

__device__ __forceinline__ u16 f2b(float f) {
    uint32_t u = __float_as_uint(f);
    u += 0x7fffu + ((u >> 16) & 1u);       // round-to-nearest-even
    return (u16)(u >> 16);
}
__device__ __forceinline__ float b2f(u16 v) {
    return __uint_as_float(((uint32_t)v) << 16);
}
__device__ __forceinline__ float sigmoid_f(float v) { return 1.f / (1.f + __expf(-v)); }
__device__ __forceinline__ float gelu_f(float v) {
    return 0.5f * v * (1.f + erff(v * 0.70710678118654752f));
}

__device__ __forceinline__ void glds16(const u16* g, u16* l) {
    __builtin_amdgcn_global_load_lds(
        (const __attribute__((address_space(1))) void*)g,
        (__attribute__((address_space(3))) void*)l, 16, 0, 0);
}

// XCD-contiguous swizzle: XCD x = l&7 owns m-tiles [8x,8x+8) for all n-tiles.
__device__ __forceinline__ void swiz8(int l, int& mt, int& nt) {
    mt = (l & 7) * 8 + ((l >> 3) & 7);
    nt = l >> 6;
}

#define ACC(i, j) ((i) < 4 ? accL[(i) & 3][(j)] : accH[(i) & 3][(j)])
#define MFMA16x32(a, b, c) __builtin_amdgcn_mfma_f32_16x16x32_bf16(a, b, c, 0, 0, 0)
#define BAR asm volatile("s_barrier" ::: "memory")

// ---------------------------------------------------------------------------
// NT GEMM, m201-style 4-phase-per-K-tile schedule. BM=256, BN=256, BK=64,
// 512 threads (8 waves 2Mx4N; per-wave 128x64, acc 32xf32x4 = 128 AGPR).
// LDS = 2 buffers x (A 256x64 + B 256x64) bf16 = 128KB. K=1024 -> 16 tiles.
//
// LDS layout (u16 idx): buf d: A at d*32768, B at d*32768+16384; row stride 64;
// row r stores global k-chunk g at phys chunk g^(r&7)  (XOR bank swizzle; the
// same family as the session's measured-0-conflict BK=32 scheme).
//
// Phases of tile kt (db=kt&1, nb=db^1). Reads issued BEFORE the barrier; MFMA
// after; closing barrier certifies all waves' reads of the phase completed
// (compiler-inserted lgkmcnt before MFMA guarantees per-wave completion):
//  p0: rd a_lo(8 b128), b_lo(4) | STAGE A_h1(kt+1)->nb | BAR | MFMA iL*jL | BAR
//  p1: rd b_hi(4)               |                      | BAR | MFMA iL*jH | BAR
//  p2: rd a_hi(8)               | STAGE B_h0(kt+2)->db | BAR | MFMA iH*jH | BAR
//  p3:                          | STAGE B_h1,A_h0(kt+2)->db
//                                                      | BAR | MFMA iH*jL | vmcnt | BAR
// Region-release proof: A(db) last read @p2 -> A_h0(kt+2)->db @p3 OK (p2-close);
// B(db) last read @p1 -> B(kt+2)->db @p2/p3 OK; A_h1(kt+1)->nb @p0: A(nb)=A(kt-1)
// last read @ kt-1 p2 OK. Landing proof: tile kt+1's newest half = A_h1 issued
// @kt p0; newer issues at kt p3's vmcnt = B_h0+B_h1+A_h0(kt+2) = 6 -> vmcnt(6)
// (m201's N=6 formula). Tail: kt=14 -> vmcnt(0); kt=15 stages nothing.
//
// MODE 0: bf16 out (N=1024), bias
// MODE 1: bf16 out (N=2048), sigmoid, interleaved bias (even->bias, odd->biasB)
// MODE 2: f32 out (N=1024) = v + bias + auxf[idx]
// MODE 3: N=2048 interleaved pair -> bf16 out (N=1024):
//         out[j] = gelu(sigmoid(v[2j]+bias[j])) * (v[2j+1]+biasB[j])
// ---------------------------------------------------------------------------
template <int MODE>
__global__ __launch_bounds__(512, 2)
void gemm8p(const u16* __restrict__ A, const u16* __restrict__ Bw,
            const float* __restrict__ bias, const float* __restrict__ biasB,
            const float* __restrict__ auxf,
            u16* __restrict__ outb, float* __restrict__ outf)
{
    __shared__ __align__(16) u16 smem[65536];   // 2 x 32768 u16 = 128KB

    int mt, nt; swiz8(blockIdx.x, mt, nt);
    const int m0 = mt * 256, n0 = nt * 256;
    const int tid = threadIdx.x;
    const int wave = tid >> 6, lane = tid & 63;
    const int wm = (wave >> 2) * 128, wn = (wave & 3) * 64;
    const int lr = lane & 15, lq = lane >> 4;

    // staging addresses: thread t -> row (t>>3), phys chunk (t&7);
    // global k-chunk = (t&7) ^ ((t>>3)&7)  (row&7 == (t>>3)&7 for all calls)
    const int kswz = ((tid & 7) ^ ((tid >> 3) & 7)) * 8;
    const u16* Ag = A + (size_t)(m0 + (tid >> 3)) * DD + kswz;
    const u16* Bg = Bw + (size_t)(n0 + (tid >> 3)) * DD + kswz;
    const int st = tid * 8;                     // u16 offset = t*16B

    // fragment-read addresses: row = base + f*16 + lr; row&7 == lr&7;
    // phys chunk = (s*4+lq) ^ (lr&7)  ->  cs1 = cs0 ^ 32
    const int cs0 = ((lq ^ (lr & 7))) * 8;
    const int cs1 = cs0 ^ 32;
    const int aLo = (wm + lr) * 64;             // a_lo rows wm..wm+63 (i*1024 each frag)
    const int bB  = (wn + lr) * 64;             // b rows wn..wn+63

    f32x4 accL[4][4] = {}, accH[4][4] = {};
    bf16x8 a_lo[4][2], a_hi[4][2], b_lo[2][2], b_hi[2][2];

    auto STA = [&](int kt, int h, int bb) {     // A half h of tile kt -> buffer bb
        u16* Ls = smem + bb * 32768 + h * 8192 + st;
        const u16* g = Ag + (size_t)(h * 128) * DD + kt * 64;
        glds16(g, Ls);
        glds16(g + (size_t)64 * DD, Ls + 4096);
    };
    auto STB = [&](int kt, int h, int bb) {
        u16* Ls = smem + bb * 32768 + 16384 + h * 8192 + st;
        const u16* g = Bg + (size_t)(h * 128) * DD + kt * 64;
        glds16(g, Ls);
        glds16(g + (size_t)64 * DD, Ls + 4096);
    };
    auto RDA4 = [&](bf16x8 (&a)[4][2], int base) {
#pragma unroll
        for (int i = 0; i < 4; i++) {
            a[i][0] = *(const bf16x8*)&smem[base + i * 1024 + cs0];
            a[i][1] = *(const bf16x8*)&smem[base + i * 1024 + cs1];
        }
    };
    auto RDB2 = [&](bf16x8 (&b)[2][2], int base) {
#pragma unroll
        for (int j = 0; j < 2; j++) {
            b[j][0] = *(const bf16x8*)&smem[base + j * 1024 + cs0];
            b[j][1] = *(const bf16x8*)&smem[base + j * 1024 + cs1];
        }
    };
    auto MM_jL = [&](bf16x8 (&a)[4][2], f32x4 (&ac)[4][4]) {   // j = 0,1 (b_lo)
        __builtin_amdgcn_s_setprio(1);
#pragma unroll
        for (int i = 0; i < 4; i++) {
            ac[i][0] = MFMA16x32(a[i][0], b_lo[0][0], ac[i][0]);
            ac[i][0] = MFMA16x32(a[i][1], b_lo[0][1], ac[i][0]);
            ac[i][1] = MFMA16x32(a[i][0], b_lo[1][0], ac[i][1]);
            ac[i][1] = MFMA16x32(a[i][1], b_lo[1][1], ac[i][1]);
        }
        __builtin_amdgcn_s_setprio(0);
    };
    auto MM_jH = [&](bf16x8 (&a)[4][2], f32x4 (&ac)[4][4]) {   // j = 2,3 (b_hi)
        __builtin_amdgcn_s_setprio(1);
#pragma unroll
        for (int i = 0; i < 4; i++) {
            ac[i][2] = MFMA16x32(a[i][0], b_hi[0][0], ac[i][2]);
            ac[i][2] = MFMA16x32(a[i][1], b_hi[0][1], ac[i][2]);
            ac[i][3] = MFMA16x32(a[i][0], b_hi[1][0], ac[i][3]);
            ac[i][3] = MFMA16x32(a[i][1], b_hi[1][1], ac[i][3]);
        }
        __builtin_amdgcn_s_setprio(0);
    };

    // prologue: tile0 -> buf0 (8 glds, oldest) + tile1 partials -> buf1 (6 glds,
    // matching the steady stagger: B_h0,B_h1 @ "p2,p3", A_h0 @ "p3")
    STA(0, 0, 0); STA(0, 1, 0); STB(0, 0, 0); STB(0, 1, 0);
    STB(1, 0, 1); STB(1, 1, 1); STA(1, 0, 1);
    asm volatile("s_waitcnt vmcnt(6)\ns_barrier" ::: "memory");   // tile0 landed

#pragma unroll 2
    for (int kt = 0; kt < 14; ++kt) {
        const int db = kt & 1, nb = db ^ 1;
        const int dbo = db * 32768;
        // p0
        RDA4(a_lo, dbo + aLo);
        RDB2(b_lo, dbo + 16384 + bB);
        STA(kt + 1, 1, nb);
        BAR;
        MM_jL(a_lo, accL);
        BAR;
        // p1
        RDB2(b_hi, dbo + 16384 + bB + 2048);
        BAR;
        MM_jH(a_lo, accL);
        BAR;
        // p2
        RDA4(a_hi, dbo + aLo + 4096);
        STB(kt + 2, 0, db);
        BAR;
        MM_jH(a_hi, accH);
        BAR;
        // p3
        STB(kt + 2, 1, db);
        STA(kt + 2, 0, db);
        BAR;
        MM_jL(a_hi, accH);
        asm volatile("s_waitcnt vmcnt(6)\ns_barrier" ::: "memory");  // tile kt+1 landed
    }
    // kt = 14 (db=0): no kt+2 stages; vmcnt(0) certifies tile 15
    {
        RDA4(a_lo, aLo);
        RDB2(b_lo, 16384 + bB);
        STA(15, 1, 1);
        BAR; MM_jL(a_lo, accL); BAR;
        RDB2(b_hi, 16384 + bB + 2048);
        BAR; MM_jH(a_lo, accL); BAR;
        RDA4(a_hi, aLo + 4096);
        BAR; MM_jH(a_hi, accH); BAR;
        BAR; MM_jL(a_hi, accH);
        asm volatile("s_waitcnt vmcnt(0)\ns_barrier" ::: "memory");
    }
    // kt = 15 (db=1): pure compute
    {
        RDA4(a_lo, 32768 + aLo);
        RDB2(b_lo, 32768 + 16384 + bB);
        BAR; MM_jL(a_lo, accL); BAR;
        RDB2(b_hi, 32768 + 16384 + bB + 2048);
        BAR; MM_jH(a_lo, accL); BAR;
        RDA4(a_hi, 32768 + aLo + 4096);
        BAR; MM_jH(a_hi, accH); BAR;
        BAR; MM_jL(a_hi, accH);
    }

    // ---------------- epilogues (C/D layout: col=lane&15, row=(lane>>4)*4+reg) ----
    if constexpr (MODE == 0 || MODE == 1) {
        constexpr int NW = (MODE == 1) ? 2048 : 1024;
        u16* ep = smem;
#pragma unroll                               // h compile-time: ACC index (rule #20)
        for (int h = 0; h < 4; ++h) {
            __syncthreads();
            if (wm == (h >> 1) * 128) {
                const int i0 = (h & 1) * 4;
#pragma unroll
                for (int ii = 0; ii < 4; ++ii) {
#pragma unroll
                    for (int j = 0; j < 4; ++j) {
                        const int col = wn + j * 16 + lr;
                        const int gc = n0 + col;
                        float bz;
                        if constexpr (MODE == 1)
                            bz = (gc & 1) ? biasB[gc >> 1] : bias[gc >> 1];
                        else
                            bz = bias[gc];
#pragma unroll
                        for (int p = 0; p < 4; ++p) {
                            float v = ACC(i0 + ii, j)[p] + bz;
                            if constexpr (MODE == 1) v = sigmoid_f(v);
                            ep[(ii * 16 + lq * 4 + p) * EPAD2 + col] = f2b(v);
                        }
                    }
                }
            }
            __syncthreads();
#pragma unroll
            for (int t = 0; t < 4; ++t) {
                const int f = t * 512 + tid;
                const int row = f >> 5, c8 = (f & 31) * 8;
                *(uint4*)&outb[(size_t)(m0 + h * 64 + row) * NW + n0 + c8] =
                    *(const uint4*)&ep[row * EPAD2 + c8];
            }
        }
    } else if constexpr (MODE == 2) {
#pragma unroll
        for (int i = 0; i < 8; ++i) {
            const int mrow = m0 + wm + (i & 3) * 16 + (i >> 2) * 64 + lq * 4;
#pragma unroll
            for (int j = 0; j < 4; ++j) {
                const int ncol = n0 + wn + j * 16 + lr;
                const float bz = bias[ncol];
#pragma unroll
                for (int p = 0; p < 4; ++p) {
                    const size_t idx = (size_t)(mrow + p) * DD + ncol;
                    outf[idx] = ((i < 4) ? accL[i & 3][j][p] : accH[i & 3][j][p])
                                + bz + auxf[idx];
                }
            }
        }
    } else {   // MODE 3: interleaved MLP combine, f32 LDS stage
        float* epf = (float*)smem;               // [64][EPADF]
#pragma unroll                               // h compile-time: ACC index (rule #20)
        for (int h = 0; h < 4; ++h) {
            __syncthreads();
            if (wm == (h >> 1) * 128) {
                const int i0 = (h & 1) * 4;
#pragma unroll
                for (int ii = 0; ii < 4; ++ii) {
#pragma unroll
                    for (int j = 0; j < 4; ++j) {
                        const int col = wn + j * 16 + lr;
                        const int gc = n0 + col;
                        const float bz = (gc & 1) ? biasB[gc >> 1] : bias[gc >> 1];
#pragma unroll
                        for (int p = 0; p < 4; ++p)
                            epf[(ii * 16 + lq * 4 + p) * EPADF + col] =
                                ACC(i0 + ii, j)[p] + bz;
                    }
                }
            }
            __syncthreads();
#pragma unroll
            for (int t = 0; t < 4; ++t) {
                const int f = t * 512 + tid;
                const int row = f >> 5, cg = (f & 31) * 4;   // 4 output cols
                const float4 v0 = *(const float4*)&epf[row * EPADF + cg * 2];
                const float4 v1 = *(const float4*)&epf[row * EPADF + cg * 2 + 4];
                ushort4 o4;
                o4.x = f2b(gelu_f(sigmoid_f(v0.x)) * v0.y);
                o4.y = f2b(gelu_f(sigmoid_f(v0.z)) * v0.w);
                o4.z = f2b(gelu_f(sigmoid_f(v1.x)) * v1.y);
                o4.w = f2b(gelu_f(sigmoid_f(v1.z)) * v1.w);
                *(ushort4*)&outb[(size_t)(m0 + h * 64 + row) * DD + (n0 >> 1) + cg] = o4;
            }
        }
    }
}

// ---------------------------------------------------------------------------
// RMSNorm: one block per row; out bf16 = x/max(||x||,1e-12)*sqrt(D)*g
// ---------------------------------------------------------------------------
__global__ __launch_bounds__(256)
void rmsnorm_k(const float* __restrict__ x, const float* __restrict__ g,
               u16* __restrict__ out)
{
    const int row = blockIdx.x;
    const int t = threadIdx.x;
    const float4 v = ((const float4*)(x + (size_t)row * DD))[t];
    float ss = v.x * v.x + v.y * v.y + v.z * v.z + v.w * v.w;
#pragma unroll
    for (int o = 32; o > 0; o >>= 1) ss += __shfl_down(ss, o, 64);
    __shared__ float wsum[4];
    if ((t & 63) == 0) wsum[t >> 6] = ss;
    __syncthreads();
    const float tot = wsum[0] + wsum[1] + wsum[2] + wsum[3];
    const float sc = 32.0f * rsqrtf(fmaxf(tot, 1e-24f));
    const float4 gv = ((const float4*)g)[t];
    ushort4 o4;
    o4.x = f2b(v.x * sc * gv.x);
    o4.y = f2b(v.y * sc * gv.y);
    o4.z = f2b(v.z * sc * gv.z);
    o4.w = f2b(v.w * sc * gv.w);
    ((ushort4*)(out + (size_t)row * DD))[t] = o4;
}

// ---------------------------------------------------------------------------
// fp32 -> bf16 weight conversion.
// conv_plain: 4 plain matrices. conv_inter: 2 row-interleaved pairs
// (dst row 2j = srcA row j, dst row 2j+1 = srcB row j).
// ---------------------------------------------------------------------------
struct WP { const float* s[4]; unsigned off[4]; };
__global__ __launch_bounds__(256)
void conv_plain(WP w, u16* __restrict__ out)
{
    const float* in = w.s[blockIdx.y];
    u16* o = out + (size_t)w.off[blockIdx.y];
    const int i = (blockIdx.x * 256 + threadIdx.x) * 4;
    const float4 v = *(const float4*)(in + i);
    ushort4 r;
    r.x = f2b(v.x); r.y = f2b(v.y); r.z = f2b(v.z); r.w = f2b(v.w);
    *(ushort4*)(o + i) = r;
}
struct WI { const float* a[2]; const float* b[2]; unsigned off[2]; };
__global__ __launch_bounds__(256)
void conv_inter(WI w, u16* __restrict__ out)
{
    u16* o = out + (size_t)w.off[blockIdx.y];
    const int e = (blockIdx.x * 256 + threadIdx.x) * 4;   // < 2M
    const int row = e >> 10, col = e & 1023;
    const float* src = (row & 1) ? w.b[blockIdx.y] : w.a[blockIdx.y];
    const float4 v = *(const float4*)(src + ((size_t)(row >> 1) << 10) + col);
    ushort4 r;
    r.x = f2b(v.x); r.y = f2b(v.y); r.z = f2b(v.z); r.w = f2b(v.w);
    *(ushort4*)(o + e) = r;
}

// ---------------------------------------------------------------------------
// RG-LRU chunked scan, interleaved rt/it input (col 2d = rt, 2d+1 = it).
// h[t] = a[t]*h[t-1] + g[t]; a = exp(log_a * rt / 8); g = sqrt(1-a^2)*it*x
// ---------------------------------------------------------------------------
__global__ __launch_bounds__(256)
void scan_chunks(const u16* __restrict__ rtit, const u16* __restrict__ rg,
                 const float* __restrict__ Lam,
                 float* __restrict__ P, float* __restrict__ Hl)
{
    const int d = blockIdx.x * 256 + threadIdx.x;
    const int c = blockIdx.y, b = blockIdx.z;
    const float k = -log1pf(__expf(-Lam[d])) * 0.125f;
    const size_t base1 = (((size_t)b * 4096) + (size_t)c * CLEN) * DD + d;
    const size_t base2 = (((size_t)b * 4096) + (size_t)c * CLEN) * 2048 + 2 * d;
    float p = 1.f, h = 0.f;
#pragma unroll 4
    for (int t = 0; t < CLEN; t++) {
        const uint32_t w = *(const uint32_t*)&rtit[base2 + (size_t)t * 2048];
        const float r = b2f((u16)(w & 0xffffu));
        const float i = b2f((u16)(w >> 16));
        const float xv = b2f(rg[base1 + (size_t)t * DD]);
        const float a = __expf(k * r);
        const float g = sqrtf(fmaxf(1.f - a * a, 0.f)) * (i * xv);
        p *= a;
        h = fmaf(a, h, g);
    }
    const int o = (b * NCH + c) * DD + d;
    P[o] = p;
    Hl[o] = h;
}

__global__ __launch_bounds__(256)
void scan_carry(const float* __restrict__ P, const float* __restrict__ Hl,
                float* __restrict__ Cin)
{
    const int idx = blockIdx.x * 256 + threadIdx.x;  // B*D = 4096
    const int b = idx >> 10, d = idx & 1023;
    float h = 0.f;
    for (int c = 0; c < NCH; c++) {
        const int o = (b * NCH + c) * DD + d;
        Cin[o] = h;
        h = fmaf(P[o], h, Hl[o]);
    }
}

__global__ __launch_bounds__(256)
void scan_apply(const u16* __restrict__ rtit, const u16* __restrict__ rg,
                const u16* __restrict__ lin, const float* __restrict__ Lam,
                const float* __restrict__ Cin, u16* __restrict__ yin)
{
    const int d = blockIdx.x * 256 + threadIdx.x;
    const int c = blockIdx.y, b = blockIdx.z;
    const float k = -log1pf(__expf(-Lam[d])) * 0.125f;
    const size_t base1 = (((size_t)b * 4096) + (size_t)c * CLEN) * DD + d;
    const size_t base2 = (((size_t)b * 4096) + (size_t)c * CLEN) * 2048 + 2 * d;
    float h = Cin[(b * NCH + c) * DD + d];
#pragma unroll 4
    for (int t = 0; t < CLEN; t++) {
        const uint32_t w = *(const uint32_t*)&rtit[base2 + (size_t)t * 2048];
        const float r = b2f((u16)(w & 0xffffu));
        const float i = b2f((u16)(w >> 16));
        const size_t ix = base1 + (size_t)t * DD;
        const float xv = b2f(rg[ix]);
        const float a = __expf(k * r);
        const float g = sqrtf(fmaxf(1.f - a * a, 0.f)) * (i * xv);
        h = fmaf(a, h, g);
        const float l = b2f(lin[ix]);
        yin[ix] = f2b(gelu_f(l) * h);
    }
}

// ---------------------------------------------------------------------------
extern "C" void kernel_launch(void* const* d_in, const int* in_sizes, int n_in,
                              void* d_out, int out_size, void* d_ws, size_t ws_size,
                              hipStream_t stream)
{
    const float* x      = (const float*)d_in[0];
    const float* g1     = (const float*)d_in[1];
    const float* g2     = (const float*)d_in[2];
    const float* W_lin  = (const float*)d_in[3];
    const float* b_lin  = (const float*)d_in[4];
    const float* W_conv = (const float*)d_in[5];
    const float* b_conv = (const float*)d_in[6];
    const float* W_lin2 = (const float*)d_in[7];
    const float* b_lin2 = (const float*)d_in[8];
    const float* Wa     = (const float*)d_in[9];
    const float* ba     = (const float*)d_in[10];
    const float* Wx     = (const float*)d_in[11];
    const float* bx     = (const float*)d_in[12];
    const float* Lam    = (const float*)d_in[13];
    const float* W1     = (const float*)d_in[14];
    const float* b1     = (const float*)d_in[15];
    const float* W2     = (const float*)d_in[16];
    const float* b2     = (const float*)d_in[17];
    const float* W3     = (const float*)d_in[18];
    const float* b3     = (const float*)d_in[19];
    float* out = (float*)d_out;

    char* p = (char*)d_ws;
    auto alloc = [&](size_t bytes) -> char* {
        char* q = p;
        p += (bytes + 255) & ~(size_t)255;
        return q;
    };
    const size_t MD = (size_t)MM * DD;
    const size_t M1 = (size_t)DD * DD;        // 1M elements
    u16* wball = (u16*)alloc((size_t)8 * M1 * 2);   // 16MB
    u16* t1   = (u16*)alloc(MD * 2);                // lin
    u16* t2   = (u16*)alloc(MD * 2);                // rg, later combined
    u16* t4   = (u16*)alloc(MD * 2);                // xn -> yin -> xm
    u16* rtit = (u16*)alloc(MD * 4);                // interleaved rt/it (16384x2048)
    float* res2 = (float*)alloc(MD * 4);
    float* P   = (float*)alloc((size_t)4 * NCH * DD * 4);
    float* Hl  = (float*)alloc((size_t)4 * NCH * DD * 4);
    float* Cin = (float*)alloc((size_t)4 * NCH * DD * 4);

    // wball layout (u16 elem offsets):
    //  [0]   W_lin   [1M] W_conv   [2M] WaWx(2M, interleaved)
    //  [4M]  W_lin2  [5M] W1W2(2M, interleaved)  [7M] W3
    WP wp;
    wp.s[0] = W_lin;  wp.off[0] = 0;
    wp.s[1] = W_conv; wp.off[1] = 1u << 20;
    wp.s[2] = W_lin2; wp.off[2] = 4u << 20;
    wp.s[3] = W3;     wp.off[3] = 7u << 20;
    conv_plain<<<dim3(M1 / 1024, 4), 256, 0, stream>>>(wp, wball);
    WI wi;
    wi.a[0] = Wa; wi.b[0] = Wx; wi.off[0] = 2u << 20;
    wi.a[1] = W1; wi.b[1] = W2; wi.off[1] = 5u << 20;
    conv_inter<<<dim3(2 * M1 / 1024, 2), 256, 0, stream>>>(wi, wball);

    const u16* wLin  = wball;
    const u16* wConv = wball + (1u << 20);
    const u16* wAX   = wball + (2u << 20);
    const u16* wLin2 = wball + (4u << 20);
    const u16* w12   = wball + (5u << 20);
    const u16* w3    = wball + (7u << 20);

    const int gs = (MM / 256) * (DD / 256);        // 256 blocks (N=1024)
    const int gw = (MM / 256) * (2 * DD / 256);    // 512 blocks (N=2048)
    const dim3 sg(DD / 256, NCH, 4);

    // xn = rmsnorm(x)*g1
    rmsnorm_k<<<MM, 256, 0, stream>>>(x, g1, t4);
    // lin = xn@W_lin.T + b_lin
    gemm8p<0><<<gs, 512, 0, stream>>>(t4, wLin, b_lin, nullptr, nullptr, t1, nullptr);
    // rg = lin@W_conv.T + b_conv
    gemm8p<0><<<gs, 512, 0, stream>>>(t1, wConv, b_conv, nullptr, nullptr, t2, nullptr);
    // rtit = sigmoid(rg@[Wa||Wx interleaved].T + [ba||bx])
    gemm8p<1><<<gw, 512, 0, stream>>>(t2, wAX, ba, bx, nullptr, rtit, nullptr);
    // RG-LRU scan + yin = gelu(lin)*h
    scan_chunks<<<sg, 256, 0, stream>>>(rtit, t2, Lam, P, Hl);
    scan_carry<<<4096 / 256, 256, 0, stream>>>(P, Hl, Cin);
    scan_apply<<<sg, 256, 0, stream>>>(rtit, t2, t1, Lam, Cin, t4);
    // res2 = yin@W_lin2.T + b_lin2 + x
    gemm8p<2><<<gs, 512, 0, stream>>>(t4, wLin2, b_lin2, nullptr, x, nullptr, res2);
    // xm = rmsnorm(res2)*g2
    rmsnorm_k<<<MM, 256, 0, stream>>>(res2, g2, t4);
    // combined = gelu(sigmoid(xm@W1.T+b1)) * (xm@W2.T+b2)   (interleaved pair GEMM)
    gemm8p<3><<<gw, 512, 0, stream>>>(t4, w12, b1, b2, nullptr, t2, nullptr);
    // y = combined@W3.T + b3 + res2
    gemm8p<2><<<gs, 512, 0, stream>>>(t2, w3, b3, nullptr, res2, nullptr, out);
}